// Round 14
// baseline (59.361 us; speedup 1.0000x reference)
//
#include <hip/hip_runtime.h>

// RecPolicy: per-row bidirectional GRU (H=2) + obs linear + scalar head.
// x: (B,18) f32 = [obs(4), j(7), jd(7)] ; out: (B,7) f32
//
// R14 = producer/consumer wave specialization (AITER pattern).
// 512-thread blocks: wave 0 streams 448-row tiles into double-buffered LDS
// via global_load_lds DMA; waves 1-7 are pure-compute consumers (64 rows
// each) with ZERO VMEM dependencies (only ds_read + fire-and-forget stores).
// One __syncthreads per tile: its implicit vmcnt(0) drains the DMA, and the
// barrier also proves consumers are done with the buffer the producer fills
// next. Memory streams continuously on a dedicated wave -> compute-bound.
// Evidence: R9 marginal compute=34us, HBM=19us, 8 same-wave structures all
// = 53 = sum (intra-wave vmcnt convoy).

using v2f = __attribute__((ext_vector_type(2))) float;

__device__ __forceinline__ float fexp2(float x) { return __builtin_amdgcn_exp2f(x); }
__device__ __forceinline__ float frcp(float x)  { return __builtin_amdgcn_rcpf(x); }

struct Cell {
    v2f wr0, wr1, ur0, ur1, br;   // r gates, prescaled by -log2(e)
    v2f wz0, wz1, uz0, uz1, bz;   // z gates, prescaled by -log2(e)
    v2f wn0, wn1, bni;            // n input part, prescaled by 2*log2(e)
    v2f un0, un1, bnh;            // n hidden part, prescaled by 2*log2(e)
};

// ---- setup kernel: prescale weights once into d_ws ----
// ws layout (floats): [0..31] up Cell, [64..95] dn Cell,
//                     [128..139] w_obs, [140..141] b_obs,
//                     [142..143] w_out, [144] b_out
__global__ void prep_kernel(
    const float* __restrict__ w_ih_up, const float* __restrict__ w_hh_up,
    const float* __restrict__ b_ih_up, const float* __restrict__ b_hh_up,
    const float* __restrict__ w_obs,   const float* __restrict__ b_obs,
    const float* __restrict__ w_ih_dn, const float* __restrict__ w_hh_dn,
    const float* __restrict__ b_ih_dn, const float* __restrict__ b_hh_dn,
    const float* __restrict__ w_out,   const float* __restrict__ b_out,
    float* __restrict__ ws)
{
    if (threadIdx.x != 0 || blockIdx.x != 0) return;
    const float s1 = -1.4426950408889634f;  // -log2(e)
    const float s2 =  2.8853900817779268f;  // 2*log2(e)
    #pragma unroll
    for (int c = 0; c < 2; ++c) {
        const float* wi = c ? w_ih_dn : w_ih_up;
        const float* wh = c ? w_hh_dn : w_hh_up;
        const float* bi = c ? b_ih_dn : b_ih_up;
        const float* bh = c ? b_hh_dn : b_hh_up;
        float* o = ws + c * 64;
        o[0] = s1*wi[0]; o[1] = s1*wi[2];  o[2] = s1*wi[1]; o[3] = s1*wi[3];
        o[4] = s1*wh[0]; o[5] = s1*wh[2];  o[6] = s1*wh[1]; o[7] = s1*wh[3];
        o[8] = s1*(bi[0]+bh[0]); o[9] = s1*(bi[1]+bh[1]);
        o[10] = s1*wi[4]; o[11] = s1*wi[6]; o[12] = s1*wi[5]; o[13] = s1*wi[7];
        o[14] = s1*wh[4]; o[15] = s1*wh[6]; o[16] = s1*wh[5]; o[17] = s1*wh[7];
        o[18] = s1*(bi[2]+bh[2]); o[19] = s1*(bi[3]+bh[3]);
        o[20] = s2*wi[8]; o[21] = s2*wi[10]; o[22] = s2*wi[9]; o[23] = s2*wi[11];
        o[24] = s2*bi[4]; o[25] = s2*bi[5];
        o[26] = s2*wh[8]; o[27] = s2*wh[10]; o[28] = s2*wh[9]; o[29] = s2*wh[11];
        o[30] = s2*bh[4]; o[31] = s2*bh[5];
    }
    #pragma unroll
    for (int i = 0; i < 12; ++i) ws[128 + i] = w_obs[i];
    ws[140] = b_obs[0]; ws[141] = b_obs[1];
    ws[142] = w_out[0]; ws[143] = w_out[1];
    ws[144] = b_out[0];
}

// paired-rcp GRU cell: 6 exp2 + 3 rcp
__device__ __forceinline__ void gru(const Cell& c, float x0, float x1, v2f& h) {
    v2f gr = c.br + c.wr0 * x0 + c.wr1 * x1 + c.ur0 * h.x + c.ur1 * h.y;
    v2f gz = c.bz + c.wz0 * x0 + c.wz1 * x1 + c.uz0 * h.x + c.uz1 * h.y;
    v2f dr = (v2f){1.0f + fexp2(gr.x), 1.0f + fexp2(gr.y)};
    v2f dz = (v2f){1.0f + fexp2(gz.x), 1.0f + fexp2(gz.y)};
    float invr = frcp(dr.x * dr.y);
    v2f r = invr * (v2f){dr.y, dr.x};
    v2f gi = c.bni + c.wn0 * x0 + c.wn1 * x1;
    v2f gh = c.bnh + c.un0 * h.x + c.un1 * h.y;
    v2f a  = gi + r * gh;
    v2f da = (v2f){1.0f + fexp2(a.x), 1.0f + fexp2(a.y)};
    float m = -2.0f * frcp(da.x * da.y);
    v2f n = (v2f){fmaf(m, da.y, 1.0f), fmaf(m, da.x, 1.0f)};
    float invz = frcp(dz.x * dz.y);
    v2f z = invz * (v2f){dz.y, dz.x};
    h = n + z * (h - n);
}

// full per-row chain from an 18-float row (registers), writing 7 acts
__device__ __forceinline__ void row_chain(
    const Cell& up, const Cell& dn, const float* __restrict__ W,
    const float* row, float acts[7])
{
    v2f h = (v2f){0.0f, 0.0f};
    v2f hu[7];
    #pragma unroll
    for (int k = 0; k < 7; ++k) {
        const int i = 6 - k;
        gru(up, row[4 + i], row[11 + i], h);
        hu[k] = h;
    }
    {
        v2f t = (v2f){W[140], W[141]};
        #pragma unroll
        for (int c = 0; c < 4; ++c)
            t += (v2f){W[128 + c], W[134 + c]} * row[c];
        t += (v2f){W[132], W[138]} * h.x;
        t += (v2f){W[133], W[139]} * h.y;
        h = t;
    }
    const float wo0 = W[142], wo1 = W[143], bo = W[144];
    #pragma unroll
    for (int k = 0; k < 7; ++k) {
        gru(dn, hu[k].x, hu[k].y, h);
        acts[k] = fmaf(wo0, h.x, fmaf(wo1, h.y, bo));
    }
}

// DMA one 448-row tile (32256 B) into LDS: 31 x 1KB (16B/lane) + 2 x 256B
// (4B/lane). LDS dest is wave-uniform base (+lane*size by HW); global src
// is per-lane. Pattern proven correct in R13.
__device__ __forceinline__ void dma_tile448(const float* __restrict__ x,
                                            long t, float* dstlds, int lane)
{
    const char* g = reinterpret_cast<const char*>(x) + t * 32256;
    char* l = reinterpret_cast<char*>(dstlds);
    #pragma unroll
    for (int k = 0; k < 31; ++k)
        __builtin_amdgcn_global_load_lds(
            (const __attribute__((address_space(1))) void*)(g + k * 1024 + lane * 16),
            (__attribute__((address_space(3))) void*)(l + k * 1024), 16, 0, 0);
    #pragma unroll
    for (int c = 0; c < 2; ++c)
        __builtin_amdgcn_global_load_lds(
            (const __attribute__((address_space(1))) void*)(g + 31744 + c * 256 + lane * 4),
            (__attribute__((address_space(3))) void*)(l + 31744 + c * 256), 4, 0, 0);
}

#define TILE_ROWS 448
#define TILE_F    8064            // 448*18 floats

__global__ __launch_bounds__(512) void recpolicy_kernel(
    const float* __restrict__ x, const float* __restrict__ W,
    float* __restrict__ out, int n)
{
    // 2 input buffers (2*8064) + 7 consumer out-stages (7*448) = 19264 f = 75.25 KB
    __shared__ float lds[2 * TILE_F + 7 * 448];
    const int tid  = threadIdx.x;
    const int wid  = tid >> 6;          // 0 = producer, 1..7 = consumers
    const int lane = tid & 63;

    const Cell up = *reinterpret_cast<const Cell*>(W);
    const Cell dn = *reinterpret_cast<const Cell*>(W + 64);

    const int NT = n / TILE_ROWS;       // full tiles
    const int S  = gridDim.x;           // tile stride (persistent blocks)
    int t = blockIdx.x;

    if (t < NT) {
        int cur = 0;
        if (wid == 0) dma_tile448(x, (long)t, lds, lane);   // prologue
        while (true) {
            if (wid == 0) asm volatile("s_waitcnt vmcnt(0)" ::: "memory");
            // Barrier: (a) buf[cur] DMA complete & visible (implicit vmcnt
            // drain on producer), (b) consumers finished reading buf[cur^1]
            // last iteration -> producer may overwrite it now.
            __syncthreads();

            const int tn = t + S;
            if (wid == 0) {
                if (tn < NT)
                    dma_tile448(x, (long)tn, lds + (cur ^ 1) * TILE_F, lane);
                // producer idles rest of iteration; DMA streams under compute
            } else {
                const int c = wid - 1;                  // consumer index 0..6
                const float* row = lds + cur * TILE_F + (c * 64 + lane) * 18;
                float rowv[18];
                {
                    const float2* rp = reinterpret_cast<const float2*>(row);
                    #pragma unroll
                    for (int i = 0; i < 9; ++i) {
                        float2 v = rp[i];
                        rowv[2 * i] = v.x; rowv[2 * i + 1] = v.y;
                    }
                }
                float acts[7];
                row_chain(up, dn, W, rowv, acts);

                // stage 64x7 in wave-private slice, coalesced float4 store
                float* outb = lds + 2 * TILE_F + c * 448;
                #pragma unroll
                for (int k = 0; k < 7; ++k) outb[lane * 7 + k] = acts[k];
                {
                    const float4* so = reinterpret_cast<const float4*>(outb);
                    float4* dsto = reinterpret_cast<float4*>(out)
                                 + (size_t)t * 784 + c * 112;
                    dsto[lane] = so[lane];
                    if (lane < 48) dsto[lane + 64] = so[lane + 64];
                }
            }

            if (tn >= NT) break;
            t = tn; cur ^= 1;
        }
    }

    // ---- tail rows (n % 448; 64 rows for B = 2^21), block 0 consumers ----
    const int tail0 = NT * TILE_ROWS;
    if (blockIdx.x == 0 && wid >= 1 && tail0 < n) {
        const int rg = tail0 + (wid - 1) * 64 + lane;
        if (rg < n) {
            float rowl[18];
            #pragma unroll
            for (int i = 0; i < 18; ++i) rowl[i] = x[(size_t)rg * 18 + i];
            float acts[7];
            row_chain(up, dn, W, rowl, acts);
            #pragma unroll
            for (int k = 0; k < 7; ++k) out[(size_t)rg * 7 + k] = acts[k];
        }
    }
}

extern "C" void kernel_launch(void* const* d_in, const int* in_sizes, int n_in,
                              void* d_out, int out_size, void* d_ws, size_t ws_size,
                              hipStream_t stream) {
    const float* x       = (const float*)d_in[0];
    const float* w_ih_up = (const float*)d_in[1];
    const float* w_hh_up = (const float*)d_in[2];
    const float* b_ih_up = (const float*)d_in[3];
    const float* b_hh_up = (const float*)d_in[4];
    const float* w_obs   = (const float*)d_in[5];
    const float* b_obs   = (const float*)d_in[6];
    const float* w_ih_dn = (const float*)d_in[7];
    const float* w_hh_dn = (const float*)d_in[8];
    const float* b_ih_dn = (const float*)d_in[9];
    const float* b_hh_dn = (const float*)d_in[10];
    const float* w_out   = (const float*)d_in[11];
    const float* b_out   = (const float*)d_in[12];
    float* out = (float*)d_out;
    float* ws  = (float*)d_ws;

    prep_kernel<<<1, 64, 0, stream>>>(
        w_ih_up, w_hh_up, b_ih_up, b_hh_up, w_obs, b_obs,
        w_ih_dn, w_hh_dn, b_ih_dn, b_hh_dn, w_out, b_out, ws);

    const int n = in_sizes[0] / 18;   // 2097152
    recpolicy_kernel<<<512, 512, 0, stream>>>(x, ws, out, n);
}

// Round 15
// 51.239 us; speedup vs baseline: 1.1585x; 1.1585x over previous
//
#include <hip/hip_runtime.h>

// RecPolicy: per-row bidirectional GRU (H=2) + obs linear + scalar head.
// x: (B,18) f32 = [obs(4), j(7), jd(7)] ; out: (B,7) f32
//
// R15 = R12 (best: 52.1us; direct per-lane loads, zero barriers) + exact
// z/tanh algebraic fold:  h' = [F(E-1) + h(E+1)] / [(E+1)(1+F)]
// with F=e^{-gz}, E=e^{2a} -> per cell 6 exp2 + 2 rcp (was 6+3).
// Model: trans = 16 cyc/wave64 (R9 marginal 2650 cyc/tile = 294 VALU x2 +
// 126 trans x16), so -14 trans/row predicts ~-3us. Exact math, no approx.

using v2f = __attribute__((ext_vector_type(2))) float;

__device__ __forceinline__ float fexp2(float x) { return __builtin_amdgcn_exp2f(x); }
__device__ __forceinline__ float frcp(float x)  { return __builtin_amdgcn_rcpf(x); }

struct Cell {
    v2f wr0, wr1, ur0, ur1, br;   // r gates, prescaled by -log2(e)
    v2f wz0, wz1, uz0, uz1, bz;   // z gates, prescaled by -log2(e)
    v2f wn0, wn1, bni;            // n input part, prescaled by 2*log2(e)
    v2f un0, un1, bnh;            // n hidden part, prescaled by 2*log2(e)
};

// ---- setup kernel: prescale weights once into d_ws ----
// ws layout (floats): [0..31] up Cell, [64..95] dn Cell,
//                     [128..139] w_obs, [140..141] b_obs,
//                     [142..143] w_out, [144] b_out
__global__ void prep_kernel(
    const float* __restrict__ w_ih_up, const float* __restrict__ w_hh_up,
    const float* __restrict__ b_ih_up, const float* __restrict__ b_hh_up,
    const float* __restrict__ w_obs,   const float* __restrict__ b_obs,
    const float* __restrict__ w_ih_dn, const float* __restrict__ w_hh_dn,
    const float* __restrict__ b_ih_dn, const float* __restrict__ b_hh_dn,
    const float* __restrict__ w_out,   const float* __restrict__ b_out,
    float* __restrict__ ws)
{
    if (threadIdx.x != 0 || blockIdx.x != 0) return;
    const float s1 = -1.4426950408889634f;  // -log2(e)
    const float s2 =  2.8853900817779268f;  // 2*log2(e)
    #pragma unroll
    for (int c = 0; c < 2; ++c) {
        const float* wi = c ? w_ih_dn : w_ih_up;
        const float* wh = c ? w_hh_dn : w_hh_up;
        const float* bi = c ? b_ih_dn : b_ih_up;
        const float* bh = c ? b_hh_dn : b_hh_up;
        float* o = ws + c * 64;
        o[0] = s1*wi[0]; o[1] = s1*wi[2];  o[2] = s1*wi[1]; o[3] = s1*wi[3];
        o[4] = s1*wh[0]; o[5] = s1*wh[2];  o[6] = s1*wh[1]; o[7] = s1*wh[3];
        o[8] = s1*(bi[0]+bh[0]); o[9] = s1*(bi[1]+bh[1]);
        o[10] = s1*wi[4]; o[11] = s1*wi[6]; o[12] = s1*wi[5]; o[13] = s1*wi[7];
        o[14] = s1*wh[4]; o[15] = s1*wh[6]; o[16] = s1*wh[5]; o[17] = s1*wh[7];
        o[18] = s1*(bi[2]+bh[2]); o[19] = s1*(bi[3]+bh[3]);
        o[20] = s2*wi[8]; o[21] = s2*wi[10]; o[22] = s2*wi[9]; o[23] = s2*wi[11];
        o[24] = s2*bi[4]; o[25] = s2*bi[5];
        o[26] = s2*wh[8]; o[27] = s2*wh[10]; o[28] = s2*wh[9]; o[29] = s2*wh[11];
        o[30] = s2*bh[4]; o[31] = s2*bh[5];
    }
    #pragma unroll
    for (int i = 0; i < 12; ++i) ws[128 + i] = w_obs[i];
    ws[140] = b_obs[0]; ws[141] = b_obs[1];
    ws[142] = w_out[0]; ws[143] = w_out[1];
    ws[144] = b_out[0];
}

// folded GRU cell: 6 exp2 + 2 rcp (exact algebra, no approximation)
//   G = e^{-gr}; r = 1/(1+G)                       (pair-shared rcp)
//   a = gi + r*gh (s2-scaled); E = e^{2a}; F = e^{-gz}
//   h' = (F(E-1) + h(E+1)) / ((E+1)(1+F))          (pair-shared rcp)
__device__ __forceinline__ void gru(const Cell& c, float x0, float x1, v2f& h) {
    v2f gr = c.br + c.wr0 * x0 + c.wr1 * x1 + c.ur0 * h.x + c.ur1 * h.y;
    v2f gz = c.bz + c.wz0 * x0 + c.wz1 * x1 + c.uz0 * h.x + c.uz1 * h.y;
    v2f G  = (v2f){fexp2(gr.x), fexp2(gr.y)};
    v2f Gp = G + 1.0f;
    float invr = frcp(Gp.x * Gp.y);
    v2f r = invr * (v2f){Gp.y, Gp.x};
    v2f gi = c.bni + c.wn0 * x0 + c.wn1 * x1;
    v2f gh = c.bnh + c.un0 * h.x + c.un1 * h.y;
    v2f a  = gi + r * gh;
    v2f E  = (v2f){fexp2(a.x), fexp2(a.y)};
    v2f F  = (v2f){fexp2(gz.x), fexp2(gz.y)};
    v2f Ep = E + 1.0f;
    v2f Fp = F + 1.0f;
    v2f num = F * (E - 1.0f) + h * Ep;
    v2f den = Ep * Fp;
    float invd = frcp(den.x * den.y);
    v2f t = invd * (v2f){den.y, den.x};
    h = num * t;
}

// full per-row chain from an 18-float row (registers), writing 7 acts
__device__ __forceinline__ void row_chain(
    const Cell& up, const Cell& dn, const float* __restrict__ W,
    const float* row, float acts[7])
{
    v2f h = (v2f){0.0f, 0.0f};
    v2f hu[7];
    #pragma unroll
    for (int k = 0; k < 7; ++k) {
        const int i = 6 - k;
        gru(up, row[4 + i], row[11 + i], h);
        hu[k] = h;
    }
    {
        v2f t = (v2f){W[140], W[141]};
        #pragma unroll
        for (int c = 0; c < 4; ++c)
            t += (v2f){W[128 + c], W[134 + c]} * row[c];
        t += (v2f){W[132], W[138]} * h.x;
        t += (v2f){W[133], W[139]} * h.y;
        h = t;
    }
    const float wo0 = W[142], wo1 = W[143], bo = W[144];
    #pragma unroll
    for (int k = 0; k < 7; ++k) {
        gru(dn, hu[k].x, hu[k].y, h);
        acts[k] = fmaf(wo0, h.x, fmaf(wo1, h.y, bo));
    }
}

__global__ __launch_bounds__(256) void recpolicy_kernel(
    const float* __restrict__ x, const float* __restrict__ W,
    float* __restrict__ out, int n)
{
    __shared__ float sout[1792];           // 4 waves x 448 floats = 7 KiB
    const int tid  = threadIdx.x;
    const int wid  = tid >> 6;
    const int lane = tid & 63;
    float* wout = sout + wid * 448;

    // wave-uniform prescaled weights (constant indices -> s_load)
    const Cell up = *reinterpret_cast<const Cell*>(W);
    const Cell dn = *reinterpret_cast<const Cell*>(W + 64);

    const int gw = (blockIdx.x << 2) | wid;      // global wave id
    const int rowbase = gw << 6;                 // this wave's 64 rows

    if (rowbase + 64 <= n) {
        // ---- direct per-lane row load: 9 x float2 (8B-aligned, row*72) ----
        const int row = rowbase + lane;
        const float2* rp = reinterpret_cast<const float2*>(x + (size_t)row * 18);
        float rowv[18];
        #pragma unroll
        for (int i = 0; i < 9; ++i) {
            float2 v = rp[i];
            rowv[2 * i]     = v.x;
            rowv[2 * i + 1] = v.y;
        }

        float acts[7];
        row_chain(up, dn, W, rowv, acts);

        // stage 7 outputs in wave-private slice, store coalesced float4
        #pragma unroll
        for (int k = 0; k < 7; ++k) wout[lane * 7 + k] = acts[k];
        {
            const float4* so = reinterpret_cast<const float4*>(wout);
            float4* dsto = reinterpret_cast<float4*>(out) + (size_t)gw * 112;
            dsto[lane] = so[lane];
            if (lane < 48) dsto[lane + 64] = so[lane + 64];
        }
    } else if (rowbase < n) {
        // ---- tail (never taken for B = 2^21) ----
        const int rg = rowbase + lane;
        if (rg < n) {
            float rowl[18];
            #pragma unroll
            for (int i = 0; i < 18; ++i) rowl[i] = x[(size_t)rg * 18 + i];
            float acts[7];
            row_chain(up, dn, W, rowl, acts);
            #pragma unroll
            for (int k = 0; k < 7; ++k) out[(size_t)rg * 7 + k] = acts[k];
        }
    }
}

extern "C" void kernel_launch(void* const* d_in, const int* in_sizes, int n_in,
                              void* d_out, int out_size, void* d_ws, size_t ws_size,
                              hipStream_t stream) {
    const float* x       = (const float*)d_in[0];
    const float* w_ih_up = (const float*)d_in[1];
    const float* w_hh_up = (const float*)d_in[2];
    const float* b_ih_up = (const float*)d_in[3];
    const float* b_hh_up = (const float*)d_in[4];
    const float* w_obs   = (const float*)d_in[5];
    const float* b_obs   = (const float*)d_in[6];
    const float* w_ih_dn = (const float*)d_in[7];
    const float* w_hh_dn = (const float*)d_in[8];
    const float* b_ih_dn = (const float*)d_in[9];
    const float* b_hh_dn = (const float*)d_in[10];
    const float* w_out   = (const float*)d_in[11];
    const float* b_out   = (const float*)d_in[12];
    float* out = (float*)d_out;
    float* ws  = (float*)d_ws;

    prep_kernel<<<1, 64, 0, stream>>>(
        w_ih_up, w_hh_up, b_ih_up, b_hh_up, w_obs, b_obs,
        w_ih_dn, w_hh_dn, b_ih_dn, b_hh_dn, w_out, b_out, ws);

    const int n = in_sizes[0] / 18;   // 2097152
    const int grid = (n + 255) / 256; // 4 waves/block, 64 rows/wave
    recpolicy_kernel<<<grid, 256, 0, stream>>>(x, ws, out, n);
}